// Round 1
// baseline (10882.038 us; speedup 1.0000x reference)
//
#include <hip/hip_runtime.h>

// Problem constants (B,S,D,H = 64,512,1024,1024)
#define S_LEN 512
#define BATCH 64
#define HDIM  1024
#define GDIM  3072   // 3*H

typedef __attribute__((ext_vector_type(8))) short bf16x8;           // MFMA A/B frag (8 bf16)
typedef __attribute__((ext_vector_type(4))) float f32x4;            // MFMA C/D frag
typedef __attribute__((ext_vector_type(4))) unsigned short u16x4;   // 4 bf16 store

__device__ inline unsigned short f2bf(float f) {
  unsigned u = __builtin_bit_cast(unsigned, f);
  u += 0x7fffu + ((u >> 16) & 1u);          // RNE (inputs are normal floats)
  return (unsigned short)(u >> 16);
}
__device__ inline float bf2f(unsigned short h) {
  unsigned u = ((unsigned)h) << 16;
  return __builtin_bit_cast(float, u);
}
__device__ inline bf16x8 pack8(float4 a, float4 b) {
  bf16x8 r;
  r[0] = (short)f2bf(a.x); r[1] = (short)f2bf(a.y);
  r[2] = (short)f2bf(a.z); r[3] = (short)f2bf(a.w);
  r[4] = (short)f2bf(b.x); r[5] = (short)f2bf(b.y);
  r[6] = (short)f2bf(b.z); r[7] = (short)f2bf(b.w);
  return r;
}

// ---------------------------------------------------------------------------
// Phase 1: xg[s][g][b] = sum_d U[b][s][d] * Wih[g][d] + bih[g]   (bf16 out)
// 128x128 tile, BK=32, 4 waves (2x2), 4x4 16x16x32 MFMA per wave.
// LDS chunks XOR-swizzled (chunk ^ ((row>>1)&3)) to kill the 64B-row 8-way
// bank conflict on ds_read_b128.
// ---------------------------------------------------------------------------
__global__ __launch_bounds__(256, 2) void xg_gemm(
    const float* __restrict__ U, const float* __restrict__ Wih,
    const float* __restrict__ bih, unsigned short* __restrict__ xg) {
  __shared__ bf16x8 Asub[512];   // 128 rows x 4 chunks (8KB)
  __shared__ bf16x8 Bsub[512];

  const int bid = blockIdx.x;
  const int nt = bid % 24;       // N-tile (gate cols) fastest: W_ih L2 reuse
  const int mt = bid / 24;
  const int tid = threadIdx.x;
  const int wave = tid >> 6, lane = tid & 63;
  const int q = lane >> 4, l15 = lane & 15;
  const int wm = wave >> 1, wn = wave & 1;

  // staging: thread -> (row, k-half)
  const int srow = tid >> 1, shalf = tid & 1;
  const int arow = mt * 128 + srow;            // M index = s*64+b ordering
  const float* Ag = U + ((size_t)(arow & 63) * S_LEN + (arow >> 6)) * HDIM + shalf * 16;
  const float* Bg = Wih + (size_t)(nt * 128 + srow) * HDIM + shalf * 16;
  const int sw = (srow >> 1) & 3;
  const int slot0 = srow * 4 + ((shalf * 2) ^ sw);
  const int slot1 = srow * 4 + ((shalf * 2 + 1) ^ sw);

  f32x4 acc[4][4];
#pragma unroll
  for (int i = 0; i < 4; ++i)
#pragma unroll
    for (int j = 0; j < 4; ++j) acc[i][j] = (f32x4){0.f, 0.f, 0.f, 0.f};

  for (int kk = 0; kk < 32; ++kk) {
    const float4* ap = (const float4*)(Ag + kk * 32);
    float4 a0 = ap[0], a1 = ap[1], a2 = ap[2], a3 = ap[3];
    const float4* bp = (const float4*)(Bg + kk * 32);
    float4 b0 = bp[0], b1 = bp[1], b2 = bp[2], b3 = bp[3];
    Asub[slot0] = pack8(a0, a1);
    Asub[slot1] = pack8(a2, a3);
    Bsub[slot0] = pack8(b0, b1);
    Bsub[slot1] = pack8(b2, b3);
    __syncthreads();
    bf16x8 af[4], bfr[4];
#pragma unroll
    for (int i = 0; i < 4; ++i) {
      int ar = wm * 64 + i * 16 + l15;
      af[i] = Asub[ar * 4 + (q ^ ((ar >> 1) & 3))];
      int br = wn * 64 + i * 16 + l15;
      bfr[i] = Bsub[br * 4 + (q ^ ((br >> 1) & 3))];
    }
#pragma unroll
    for (int i = 0; i < 4; ++i)
#pragma unroll
      for (int j = 0; j < 4; ++j)
        acc[i][j] = __builtin_amdgcn_mfma_f32_16x16x32_bf16(af[i], bfr[j], acc[i][j], 0, 0, 0);
    __syncthreads();
  }

  // epilogue: C row=(q*4+reg) -> M=(s,b), col=l15 -> gate col; 4 consecutive b per reg group
#pragma unroll
  for (int j = 0; j < 4; ++j) {
    int gcol = nt * 128 + wn * 64 + j * 16 + l15;
    float bias = bih[gcol];
#pragma unroll
    for (int i = 0; i < 4; ++i) {
      int rbase = mt * 128 + wm * 64 + i * 16 + q * 4;
      int s = rbase >> 6;
      int b0i = rbase & 63;
      u16x4 pk;
#pragma unroll
      for (int r = 0; r < 4; ++r) pk[r] = f2bf(acc[i][j][r] + bias);
      *(u16x4*)(xg + ((size_t)s * GDIM + gcol) * BATCH + b0i) = pk;
    }
  }
}

// ---------------------------------------------------------------------------
// Phase 2: persistent GRU scan. 64 blocks x 192 threads (3 waves).
// Block p owns h-cols [16p,16p+16). Wave g in {0,1,2} = gate {r,z,n}.
// Transposed GEMM hgT[g-row][b]: A = W_hh rows (REGISTER-resident, 128 VGPR),
// B = h[b][k] read straight from L2 (16B frags). fp32 carry in LDS.
// Device barrier: monotonic counter, agent-scope release/acquire.
// ---------------------------------------------------------------------------
__global__ __launch_bounds__(192, 1) void gru_scan(
    const float* __restrict__ Whh, const float* __restrict__ bhh,
    const unsigned short* __restrict__ xg, unsigned short* __restrict__ hbuf,
    unsigned int* __restrict__ bar, float* __restrict__ out) {
  __shared__ float gates[3][16][64];        // [gate][m][b] pre-activations
  __shared__ float hown[1024];              // [m][b] fp32 carry
  __shared__ unsigned short hstage[64 * 17];// [b][m] bf16, padded stride

  const int p = blockIdx.x;
  const int j0 = p * 16;
  const int tid = threadIdx.x;
  const int wave = tid >> 6, lane = tid & 63;
  const int q = lane >> 4, l15 = lane & 15;

  // A-operand frags: lane holds row m=l15 (W row wave*1024+j0+l15), k=kk*32+q*8+j
  bf16x8 wf[32];
  {
    const float* wrow = Whh + ((size_t)wave * HDIM + j0 + l15) * HDIM;
#pragma unroll
    for (int kk = 0; kk < 32; ++kk) {
      const float4* wp = (const float4*)(wrow + kk * 32 + q * 8);
      wf[kk] = pack8(wp[0], wp[1]);
    }
  }
  float bh[4];
#pragma unroll
  for (int r = 0; r < 4; ++r) bh[r] = bhh[wave * HDIM + j0 + q * 4 + r];

  for (int e = tid; e < 1024; e += 192) hown[e] = 0.f;
  __syncthreads();

  for (int t = 0; t < S_LEN; ++t) {
    const unsigned short* hcur = hbuf + (size_t)(t & 1) * (BATCH * HDIM);
    unsigned short* hnxt = hbuf + (size_t)((t + 1) & 1) * (BATCH * HDIM);

    // B-operand bases: n = b = nt*16 + l15, k contiguous
    const unsigned short* hb0 = hcur + (size_t)(l15) * HDIM + q * 8;
    const unsigned short* hb1 = hcur + (size_t)(16 + l15) * HDIM + q * 8;
    const unsigned short* hb2 = hcur + (size_t)(32 + l15) * HDIM + q * 8;
    const unsigned short* hb3 = hcur + (size_t)(48 + l15) * HDIM + q * 8;

    f32x4 a0 = {0.f,0.f,0.f,0.f}, a1 = a0, a2 = a0, a3 = a0;
#pragma unroll
    for (int kk = 0; kk < 32; ++kk) {
      bf16x8 h0 = *(const bf16x8*)(hb0 + kk * 32);
      bf16x8 h1 = *(const bf16x8*)(hb1 + kk * 32);
      bf16x8 h2 = *(const bf16x8*)(hb2 + kk * 32);
      bf16x8 h3 = *(const bf16x8*)(hb3 + kk * 32);
      a0 = __builtin_amdgcn_mfma_f32_16x16x32_bf16(wf[kk], h0, a0, 0, 0, 0);
      a1 = __builtin_amdgcn_mfma_f32_16x16x32_bf16(wf[kk], h1, a1, 0, 0, 0);
      a2 = __builtin_amdgcn_mfma_f32_16x16x32_bf16(wf[kk], h2, a2, 0, 0, 0);
      a3 = __builtin_amdgcn_mfma_f32_16x16x32_bf16(wf[kk], h3, a3, 0, 0, 0);
    }
    // C: row m = q*4+r, col b = nt*16+l15
#pragma unroll
    for (int r = 0; r < 4; ++r) {
      gates[wave][q * 4 + r][l15]      = a0[r] + bh[r];
      gates[wave][q * 4 + r][16 + l15] = a1[r] + bh[r];
      gates[wave][q * 4 + r][32 + l15] = a2[r] + bh[r];
      gates[wave][q * 4 + r][48 + l15] = a3[r] + bh[r];
    }
    __syncthreads();

    // combine (b-fast: coalesced xg reads, conflict-free LDS)
    for (int e = tid; e < 1024; e += 192) {
      int b = e & 63;
      int m = e >> 6;
      float hr = gates[0][m][b], hz = gates[1][m][b], hn = gates[2][m][b];
      size_t xb = ((size_t)t * GDIM + j0 + m) * BATCH + b;
      float xr = bf2f(xg[xb]);
      float xz = bf2f(xg[xb + (size_t)HDIM * BATCH]);
      float xn = bf2f(xg[xb + (size_t)2 * HDIM * BATCH]);
      float r = 1.f / (1.f + __expf(-(xr + hr)));
      float z = 1.f / (1.f + __expf(-(xz + hz)));
      float ex = __expf(2.f * (xn + r * hn));
      float n = 1.f - 2.f / (ex + 1.f);       // tanh
      float hold = hown[m * 64 + b];
      float hnew = (1.f - z) * n + z * hold;
      hown[m * 64 + b] = hnew;
      hstage[b * 17 + m] = f2bf(hnew);
    }
    __syncthreads();

    // write h_next (m-fast: 32B contiguous runs per batch row)
    for (int e = tid; e < 1024; e += 192) {
      int m = e & 15;
      int b = e >> 4;
      hnxt[(size_t)b * HDIM + j0 + m] = hstage[b * 17 + m];
    }
    __syncthreads();

    // device-wide barrier (monotonic counter; agent release/acquire)
    if (tid == 0) {
      __threadfence();  // buffer_wbl2: flush this XCD's dirty h lines
      __hip_atomic_fetch_add(bar, 1u, __ATOMIC_RELEASE, __HIP_MEMORY_SCOPE_AGENT);
      unsigned target = 64u * (unsigned)(t + 1);
      unsigned spins = 0;
      while (__hip_atomic_load(bar, __ATOMIC_ACQUIRE, __HIP_MEMORY_SCOPE_AGENT) < target) {
        __builtin_amdgcn_s_sleep(1);
        if (++spins > 200000000u) break;  // safety: wrong answer beats a hang
      }
    }
    __syncthreads();
  }

  // final h -> out[b][j]  (fp32)
  for (int e = tid; e < 1024; e += 192) {
    int b = e & 63;
    int m = e >> 6;
    out[(size_t)b * HDIM + j0 + m] = hown[m * 64 + b];
  }
}

// ---------------------------------------------------------------------------
extern "C" void kernel_launch(void* const* d_in, const int* in_sizes, int n_in,
                              void* d_out, int out_size, void* d_ws, size_t ws_size,
                              hipStream_t stream) {
  const float* U   = (const float*)d_in[0];
  const float* Wih = (const float*)d_in[1];
  const float* Whh = (const float*)d_in[2];
  const float* bih = (const float*)d_in[3];
  const float* bhh = (const float*)d_in[4];
  float* out = (float*)d_out;

  char* ws = (char*)d_ws;
  const size_t XG_BYTES = (size_t)S_LEN * GDIM * BATCH * 2;  // 201326592
  unsigned short* xg   = (unsigned short*)ws;
  unsigned short* hbuf = (unsigned short*)(ws + XG_BYTES);
  const size_t H_BYTES = (size_t)2 * BATCH * HDIM * 2;       // 262144
  unsigned int* bar    = (unsigned int*)(ws + XG_BYTES + H_BYTES);

  // zero h(0) double-buffer + barrier counter (ws is poisoned 0xAA each call)
  hipMemsetAsync(ws + XG_BYTES, 0, H_BYTES + 64, stream);

  hipLaunchKernelGGL(xg_gemm, dim3((32768 / 128) * (GDIM / 128)), dim3(256), 0, stream,
                     U, Wih, bih, xg);
  hipLaunchKernelGGL(gru_scan, dim3(64), dim3(192), 0, stream,
                     Whh, bhh, xg, hbuf, bar, out);
}

// Round 2
// 10582.213 us; speedup vs baseline: 1.0283x; 1.0283x over previous
//
#include <hip/hip_runtime.h>

// Problem constants (B,S,D,H = 64,512,1024,1024)
#define S_LEN 512
#define BATCH 64
#define HDIM  1024
#define GDIM  3072   // 3*H

typedef __attribute__((ext_vector_type(8))) short bf16x8;           // MFMA A/B frag (8 bf16)
typedef __attribute__((ext_vector_type(4))) float f32x4;            // MFMA C/D frag
typedef __attribute__((ext_vector_type(4))) unsigned short u16x4;   // 4 bf16 store

__device__ inline unsigned short f2bf(float f) {
  unsigned u = __builtin_bit_cast(unsigned, f);
  u += 0x7fffu + ((u >> 16) & 1u);          // RNE (inputs are normal floats)
  return (unsigned short)(u >> 16);
}
__device__ inline float bf2f(unsigned short h) {
  unsigned u = ((unsigned)h) << 16;
  return __builtin_bit_cast(float, u);
}
__device__ inline bf16x8 pack8(float4 a, float4 b) {
  bf16x8 r;
  r[0] = (short)f2bf(a.x); r[1] = (short)f2bf(a.y);
  r[2] = (short)f2bf(a.z); r[3] = (short)f2bf(a.w);
  r[4] = (short)f2bf(b.x); r[5] = (short)f2bf(b.y);
  r[6] = (short)f2bf(b.z); r[7] = (short)f2bf(b.w);
  return r;
}

// ---------------------------------------------------------------------------
// Phase 1: xg[s][g][b] = sum_d U[b][s][d] * Wih[g][d] + bih[g]   (bf16 out)
// 128x128 tile, BK=32, 4 waves (2x2), 4x4 16x16x32 MFMA per wave.
// LDS chunks XOR-swizzled (chunk ^ ((row>>1)&3)) to kill the 64B-row 8-way
// bank conflict on ds_read_b128.  (unchanged this round)
// ---------------------------------------------------------------------------
__global__ __launch_bounds__(256, 2) void xg_gemm(
    const float* __restrict__ U, const float* __restrict__ Wih,
    const float* __restrict__ bih, unsigned short* __restrict__ xg) {
  __shared__ bf16x8 Asub[512];   // 128 rows x 4 chunks (8KB)
  __shared__ bf16x8 Bsub[512];

  const int bid = blockIdx.x;
  const int nt = bid % 24;       // N-tile (gate cols) fastest: W_ih L2 reuse
  const int mt = bid / 24;
  const int tid = threadIdx.x;
  const int wave = tid >> 6, lane = tid & 63;
  const int q = lane >> 4, l15 = lane & 15;
  const int wm = wave >> 1, wn = wave & 1;

  // staging: thread -> (row, k-half)
  const int srow = tid >> 1, shalf = tid & 1;
  const int arow = mt * 128 + srow;            // M index = s*64+b ordering
  const float* Ag = U + ((size_t)(arow & 63) * S_LEN + (arow >> 6)) * HDIM + shalf * 16;
  const float* Bg = Wih + (size_t)(nt * 128 + srow) * HDIM + shalf * 16;
  const int sw = (srow >> 1) & 3;
  const int slot0 = srow * 4 + ((shalf * 2) ^ sw);
  const int slot1 = srow * 4 + ((shalf * 2 + 1) ^ sw);

  f32x4 acc[4][4];
#pragma unroll
  for (int i = 0; i < 4; ++i)
#pragma unroll
    for (int j = 0; j < 4; ++j) acc[i][j] = (f32x4){0.f, 0.f, 0.f, 0.f};

  for (int kk = 0; kk < 32; ++kk) {
    const float4* ap = (const float4*)(Ag + kk * 32);
    float4 a0 = ap[0], a1 = ap[1], a2 = ap[2], a3 = ap[3];
    const float4* bp = (const float4*)(Bg + kk * 32);
    float4 b0 = bp[0], b1 = bp[1], b2 = bp[2], b3 = bp[3];
    Asub[slot0] = pack8(a0, a1);
    Asub[slot1] = pack8(a2, a3);
    Bsub[slot0] = pack8(b0, b1);
    Bsub[slot1] = pack8(b2, b3);
    __syncthreads();
    bf16x8 af[4], bfr[4];
#pragma unroll
    for (int i = 0; i < 4; ++i) {
      int ar = wm * 64 + i * 16 + l15;
      af[i] = Asub[ar * 4 + (q ^ ((ar >> 1) & 3))];
      int br = wn * 64 + i * 16 + l15;
      bfr[i] = Bsub[br * 4 + (q ^ ((br >> 1) & 3))];
    }
#pragma unroll
    for (int i = 0; i < 4; ++i)
#pragma unroll
      for (int j = 0; j < 4; ++j)
        acc[i][j] = __builtin_amdgcn_mfma_f32_16x16x32_bf16(af[i], bfr[j], acc[i][j], 0, 0, 0);
    __syncthreads();
  }

  // epilogue: C row=(q*4+reg) -> M=(s,b), col=l15 -> gate col
#pragma unroll
  for (int j = 0; j < 4; ++j) {
    int gcol = nt * 128 + wn * 64 + j * 16 + l15;
    float bias = bih[gcol];
#pragma unroll
    for (int i = 0; i < 4; ++i) {
      int rbase = mt * 128 + wm * 64 + i * 16 + q * 4;
      int s = rbase >> 6;
      int b0i = rbase & 63;
      u16x4 pk;
#pragma unroll
      for (int r = 0; r < 4; ++r) pk[r] = f2bf(acc[i][j][r] + bias);
      *(u16x4*)(xg + ((size_t)s * GDIM + gcol) * BATCH + b0i) = pk;
    }
  }
}

// ---------------------------------------------------------------------------
// Phase 2: persistent GRU scan. 64 blocks x 192 threads (3 waves).
// Block p owns h-cols [16p,16p+16). Wave g in {0,1,2} = gate {r,z,n}.
// Transposed GEMM hgT[g-row][b]: A = W_hh rows (REGISTER-resident, 128 VGPR),
// B = h[b][k] read from MALL (16B frags). fp32 carry in LDS.
//
// Barrier (round-2 fix): RELEASE fetch_add (one buffer_wbl2 sc1, dirty set is
// ~2KB of h -> cheap) + RELAXED polls (sc0 sc1 loads straight from MALL, NO
// cache maintenance per poll) + ONE ACQUIRE load after the spin (single
// buffer_inv sc1 per step). Round 1 did an acquire (= full L2 invalidate)
// PER POLL plus a seq_cst threadfence per step -> ~19.7us/step of TCC
// cache-maintenance serialization.
// ---------------------------------------------------------------------------
__global__ __launch_bounds__(192, 1) void gru_scan(
    const float* __restrict__ Whh, const float* __restrict__ bhh,
    const unsigned short* __restrict__ xg, unsigned short* __restrict__ hbuf,
    unsigned int* __restrict__ bar, float* __restrict__ out) {
  __shared__ float gates[3][16][64];        // [gate][m][b] pre-activations
  __shared__ float hown[1024];              // [m][b] fp32 carry
  __shared__ unsigned short hstage[64 * 17];// [b][m] bf16, padded stride

  const int p = blockIdx.x;
  const int j0 = p * 16;
  const int tid = threadIdx.x;
  const int wave = tid >> 6, lane = tid & 63;
  const int q = lane >> 4, l15 = lane & 15;

  // A-operand frags: lane holds row m=l15 (W row wave*1024+j0+l15), k=kk*32+q*8+j
  bf16x8 wf[32];
  {
    const float* wrow = Whh + ((size_t)wave * HDIM + j0 + l15) * HDIM;
#pragma unroll
    for (int kk = 0; kk < 32; ++kk) {
      const float4* wp = (const float4*)(wrow + kk * 32 + q * 8);
      wf[kk] = pack8(wp[0], wp[1]);
    }
  }
  float bh[4];
#pragma unroll
  for (int r = 0; r < 4; ++r) bh[r] = bhh[wave * HDIM + j0 + q * 4 + r];

  for (int e = tid; e < 1024; e += 192) hown[e] = 0.f;
  __syncthreads();

  for (int t = 0; t < S_LEN; ++t) {
    const unsigned short* hcur = hbuf + (size_t)(t & 1) * (BATCH * HDIM);
    unsigned short* hnxt = hbuf + (size_t)((t + 1) & 1) * (BATCH * HDIM);

    // B-operand bases: n = b = nt*16 + l15, k contiguous
    const unsigned short* hb0 = hcur + (size_t)(l15) * HDIM + q * 8;
    const unsigned short* hb1 = hcur + (size_t)(16 + l15) * HDIM + q * 8;
    const unsigned short* hb2 = hcur + (size_t)(32 + l15) * HDIM + q * 8;
    const unsigned short* hb3 = hcur + (size_t)(48 + l15) * HDIM + q * 8;

    f32x4 a0 = {0.f,0.f,0.f,0.f}, a1 = a0, a2 = a0, a3 = a0;
#pragma unroll
    for (int kk = 0; kk < 32; ++kk) {
      bf16x8 h0 = *(const bf16x8*)(hb0 + kk * 32);
      bf16x8 h1 = *(const bf16x8*)(hb1 + kk * 32);
      bf16x8 h2 = *(const bf16x8*)(hb2 + kk * 32);
      bf16x8 h3 = *(const bf16x8*)(hb3 + kk * 32);
      a0 = __builtin_amdgcn_mfma_f32_16x16x32_bf16(wf[kk], h0, a0, 0, 0, 0);
      a1 = __builtin_amdgcn_mfma_f32_16x16x32_bf16(wf[kk], h1, a1, 0, 0, 0);
      a2 = __builtin_amdgcn_mfma_f32_16x16x32_bf16(wf[kk], h2, a2, 0, 0, 0);
      a3 = __builtin_amdgcn_mfma_f32_16x16x32_bf16(wf[kk], h3, a3, 0, 0, 0);
    }
    // C: row m = q*4+r, col b = nt*16+l15
#pragma unroll
    for (int r = 0; r < 4; ++r) {
      gates[wave][q * 4 + r][l15]      = a0[r] + bh[r];
      gates[wave][q * 4 + r][16 + l15] = a1[r] + bh[r];
      gates[wave][q * 4 + r][32 + l15] = a2[r] + bh[r];
      gates[wave][q * 4 + r][48 + l15] = a3[r] + bh[r];
    }
    __syncthreads();

    // combine (b-fast: coalesced xg reads, conflict-free LDS)
    for (int e = tid; e < 1024; e += 192) {
      int b = e & 63;
      int m = e >> 6;
      float hr = gates[0][m][b], hz = gates[1][m][b], hn = gates[2][m][b];
      size_t xb = ((size_t)t * GDIM + j0 + m) * BATCH + b;
      float xr = bf2f(xg[xb]);
      float xz = bf2f(xg[xb + (size_t)HDIM * BATCH]);
      float xn = bf2f(xg[xb + (size_t)2 * HDIM * BATCH]);
      float r = 1.f / (1.f + __expf(-(xr + hr)));
      float z = 1.f / (1.f + __expf(-(xz + hz)));
      float ex = __expf(2.f * (xn + r * hn));
      float n = 1.f - 2.f / (ex + 1.f);       // tanh
      float hold = hown[m * 64 + b];
      float hnew = (1.f - z) * n + z * hold;
      hown[m * 64 + b] = hnew;
      hstage[b * 17 + m] = f2bf(hnew);
    }
    __syncthreads();

    // write h_next (m-fast: 32B contiguous runs per batch row)
    for (int e = tid; e < 1024; e += 192) {
      int m = e & 15;
      int b = e >> 4;
      hnxt[(size_t)b * HDIM + j0 + m] = hstage[b * 17 + m];
    }
    __syncthreads();

    // device-wide barrier: release add, RELAXED polls, one acquire at exit
    if (tid == 0) {
      __hip_atomic_fetch_add(bar, 1u, __ATOMIC_RELEASE, __HIP_MEMORY_SCOPE_AGENT);
      unsigned target = 64u * (unsigned)(t + 1);
      unsigned spins = 0;
      while (__hip_atomic_load(bar, __ATOMIC_RELAXED, __HIP_MEMORY_SCOPE_AGENT) < target) {
        __builtin_amdgcn_s_sleep(1);
        if (++spins > 100000000u) break;  // safety: wrong answer beats a hang
      }
      (void)__hip_atomic_load(bar, __ATOMIC_ACQUIRE, __HIP_MEMORY_SCOPE_AGENT);
    }
    __syncthreads();
  }

  // final h -> out[b][j]  (fp32)
  for (int e = tid; e < 1024; e += 192) {
    int b = e & 63;
    int m = e >> 6;
    out[(size_t)b * HDIM + j0 + m] = hown[m * 64 + b];
  }
}

// ---------------------------------------------------------------------------
extern "C" void kernel_launch(void* const* d_in, const int* in_sizes, int n_in,
                              void* d_out, int out_size, void* d_ws, size_t ws_size,
                              hipStream_t stream) {
  const float* U   = (const float*)d_in[0];
  const float* Wih = (const float*)d_in[1];
  const float* Whh = (const float*)d_in[2];
  const float* bih = (const float*)d_in[3];
  const float* bhh = (const float*)d_in[4];
  float* out = (float*)d_out;

  char* ws = (char*)d_ws;
  const size_t XG_BYTES = (size_t)S_LEN * GDIM * BATCH * 2;  // 201326592
  unsigned short* xg   = (unsigned short*)ws;
  unsigned short* hbuf = (unsigned short*)(ws + XG_BYTES);
  const size_t H_BYTES = (size_t)2 * BATCH * HDIM * 2;       // 262144
  unsigned int* bar    = (unsigned int*)(ws + XG_BYTES + H_BYTES);

  // zero h(0) double-buffer + barrier counter (ws is poisoned 0xAA each call)
  hipMemsetAsync(ws + XG_BYTES, 0, H_BYTES + 64, stream);

  hipLaunchKernelGGL(xg_gemm, dim3((32768 / 128) * (GDIM / 128)), dim3(256), 0, stream,
                     U, Wih, bih, xg);
  hipLaunchKernelGGL(gru_scan, dim3(64), dim3(192), 0, stream,
                     Whh, bhh, xg, hbuf, bar, out);
}

// Round 3
// 6359.223 us; speedup vs baseline: 1.7112x; 1.6641x over previous
//
#include <hip/hip_runtime.h>

// Problem constants (B,S,D,H = 64,512,1024,1024)
#define S_LEN 512
#define BATCH 64
#define HDIM  1024
#define GDIM  3072   // 3*H

typedef __attribute__((ext_vector_type(8))) short bf16x8;           // MFMA A/B frag (8 bf16)
typedef __attribute__((ext_vector_type(4))) float f32x4;            // MFMA C/D frag
typedef __attribute__((ext_vector_type(4))) unsigned short u16x4;   // 4 bf16 store

__device__ inline unsigned short f2bf(float f) {
  unsigned u = __builtin_bit_cast(unsigned, f);
  u += 0x7fffu + ((u >> 16) & 1u);          // RNE (inputs are normal floats)
  return (unsigned short)(u >> 16);
}
__device__ inline float bf2f(unsigned short h) {
  unsigned u = ((unsigned)h) << 16;
  return __builtin_bit_cast(float, u);
}
__device__ inline bf16x8 pack8(float4 a, float4 b) {
  bf16x8 r;
  r[0] = (short)f2bf(a.x); r[1] = (short)f2bf(a.y);
  r[2] = (short)f2bf(a.z); r[3] = (short)f2bf(a.w);
  r[4] = (short)f2bf(b.x); r[5] = (short)f2bf(b.y);
  r[6] = (short)f2bf(b.z); r[7] = (short)f2bf(b.w);
  return r;
}

// ---------------------------------------------------------------------------
// Phase 1: xg[s][g][b] = sum_d U[b][s][d] * Wih[g][d] + bih[g]   (bf16 out)
// (unchanged this round)
// ---------------------------------------------------------------------------
__global__ __launch_bounds__(256, 2) void xg_gemm(
    const float* __restrict__ U, const float* __restrict__ Wih,
    const float* __restrict__ bih, unsigned short* __restrict__ xg) {
  __shared__ bf16x8 Asub[512];   // 128 rows x 4 chunks (8KB)
  __shared__ bf16x8 Bsub[512];

  const int bid = blockIdx.x;
  const int nt = bid % 24;       // N-tile (gate cols) fastest: W_ih L2 reuse
  const int mt = bid / 24;
  const int tid = threadIdx.x;
  const int wave = tid >> 6, lane = tid & 63;
  const int q = lane >> 4, l15 = lane & 15;
  const int wm = wave >> 1, wn = wave & 1;

  const int srow = tid >> 1, shalf = tid & 1;
  const int arow = mt * 128 + srow;            // M index = s*64+b ordering
  const float* Ag = U + ((size_t)(arow & 63) * S_LEN + (arow >> 6)) * HDIM + shalf * 16;
  const float* Bg = Wih + (size_t)(nt * 128 + srow) * HDIM + shalf * 16;
  const int sw = (srow >> 1) & 3;
  const int slot0 = srow * 4 + ((shalf * 2) ^ sw);
  const int slot1 = srow * 4 + ((shalf * 2 + 1) ^ sw);

  f32x4 acc[4][4];
#pragma unroll
  for (int i = 0; i < 4; ++i)
#pragma unroll
    for (int j = 0; j < 4; ++j) acc[i][j] = (f32x4){0.f, 0.f, 0.f, 0.f};

  for (int kk = 0; kk < 32; ++kk) {
    const float4* ap = (const float4*)(Ag + kk * 32);
    float4 a0 = ap[0], a1 = ap[1], a2 = ap[2], a3 = ap[3];
    const float4* bp = (const float4*)(Bg + kk * 32);
    float4 b0 = bp[0], b1 = bp[1], b2 = bp[2], b3 = bp[3];
    Asub[slot0] = pack8(a0, a1);
    Asub[slot1] = pack8(a2, a3);
    Bsub[slot0] = pack8(b0, b1);
    Bsub[slot1] = pack8(b2, b3);
    __syncthreads();
    bf16x8 af[4], bfr[4];
#pragma unroll
    for (int i = 0; i < 4; ++i) {
      int ar = wm * 64 + i * 16 + l15;
      af[i] = Asub[ar * 4 + (q ^ ((ar >> 1) & 3))];
      int br = wn * 64 + i * 16 + l15;
      bfr[i] = Bsub[br * 4 + (q ^ ((br >> 1) & 3))];
    }
#pragma unroll
    for (int i = 0; i < 4; ++i)
#pragma unroll
      for (int j = 0; j < 4; ++j)
        acc[i][j] = __builtin_amdgcn_mfma_f32_16x16x32_bf16(af[i], bfr[j], acc[i][j], 0, 0, 0);
    __syncthreads();
  }

#pragma unroll
  for (int j = 0; j < 4; ++j) {
    int gcol = nt * 128 + wn * 64 + j * 16 + l15;
    float bias = bih[gcol];
#pragma unroll
    for (int i = 0; i < 4; ++i) {
      int rbase = mt * 128 + wm * 64 + i * 16 + q * 4;
      int s = rbase >> 6;
      int b0i = rbase & 63;
      u16x4 pk;
#pragma unroll
      for (int r = 0; r < 4; ++r) pk[r] = f2bf(acc[i][j][r] + bias);
      *(u16x4*)(xg + ((size_t)s * GDIM + gcol) * BATCH + b0i) = pk;
    }
  }
}

// ---------------------------------------------------------------------------
// Phase 2 (round-3 rewrite): persistent GRU scan, 64 blocks x 256 threads.
// Block p owns h-cols [16p,16p+16). K-SPLIT: wave w in {0..3} owns
// k in [256w, 256w+256) and computes partial pre-activations for ALL 3 gates
// (A-frags register-resident: 3 gates x 8 kk = 96 VGPRs/lane). Each wave
// reads only 32 KB of h per step (32 independent 16B loads/lane) instead of
// round-2's 128 KB/wave (128 loads, ~10us latency serialization - the real
// round-2 bottleneck; MfmaUtil was 0.8%). Cross-wave reduction via LDS
// partials. xg for step t prefetched into registers BEFORE the GEMM phase.
// ---------------------------------------------------------------------------
__global__ __launch_bounds__(256, 1) void gru_scan(
    const float* __restrict__ Whh, const float* __restrict__ bhh,
    const unsigned short* __restrict__ xg, unsigned short* __restrict__ hbuf,
    unsigned int* __restrict__ bar, float* __restrict__ out) {
  __shared__ float part[4][3][16][64];       // 48 KB: per-wave partial gates
  __shared__ float hown[1024];               // fp32 carry [m][b]
  __shared__ unsigned short hstage[64 * 20]; // [b][m] bf16, 40B rows (8B-aligned)
  __shared__ float bh_lds[3][16];

  const int p = blockIdx.x;
  const int j0 = p * 16;
  const int tid = threadIdx.x;
  const int w = tid >> 6, lane = tid & 63;
  const int q = lane >> 4, l15 = lane & 15;
  const int k0 = w * 256;

  // A-frags: wf[g][kk] = Whh[g*1024 + j0 + l15][k0 + kk*32 + q*8 .. +7]
  bf16x8 wf[3][8];
#pragma unroll
  for (int g = 0; g < 3; ++g) {
    const float* wrow = Whh + ((size_t)g * HDIM + j0 + l15) * HDIM + k0;
#pragma unroll
    for (int kk = 0; kk < 8; ++kk) {
      const float4* wp = (const float4*)(wrow + kk * 32 + q * 8);
      wf[g][kk] = pack8(wp[0], wp[1]);
    }
  }
  if (tid < 48) bh_lds[tid >> 4][tid & 15] = bhh[(tid >> 4) * HDIM + j0 + (tid & 15)];
  for (int e = tid; e < 1024; e += 256) hown[e] = 0.f;
  __syncthreads();

  for (int t = 0; t < S_LEN; ++t) {
    const unsigned short* hcur = hbuf + (size_t)(t & 1) * (BATCH * HDIM);
    unsigned short* hnxt = hbuf + (size_t)((t + 1) & 1) * (BATCH * HDIM);

    // prefetch xg for this step (independent of h; hides HBM latency under GEMM)
    unsigned short xq[3][4];
#pragma unroll
    for (int i = 0; i < 4; ++i) {
      int e = tid + 256 * i;
      int m = e >> 6, b = e & 63;
      size_t base = ((size_t)t * GDIM + j0 + m) * BATCH + b;
      xq[0][i] = xg[base];
      xq[1][i] = xg[base + (size_t)HDIM * BATCH];
      xq[2][i] = xg[base + (size_t)2 * HDIM * BATCH];
    }

    f32x4 acc[3][4];
#pragma unroll
    for (int g = 0; g < 3; ++g)
#pragma unroll
      for (int bt = 0; bt < 4; ++bt) acc[g][bt] = (f32x4){0.f, 0.f, 0.f, 0.f};

    const unsigned short* hb = hcur + k0 + q * 8;
#pragma unroll
    for (int kk = 0; kk < 8; ++kk) {
      bf16x8 h0 = *(const bf16x8*)(hb + (size_t)(l15) * HDIM + kk * 32);
      bf16x8 h1 = *(const bf16x8*)(hb + (size_t)(16 + l15) * HDIM + kk * 32);
      bf16x8 h2 = *(const bf16x8*)(hb + (size_t)(32 + l15) * HDIM + kk * 32);
      bf16x8 h3 = *(const bf16x8*)(hb + (size_t)(48 + l15) * HDIM + kk * 32);
#pragma unroll
      for (int g = 0; g < 3; ++g) {
        acc[g][0] = __builtin_amdgcn_mfma_f32_16x16x32_bf16(wf[g][kk], h0, acc[g][0], 0, 0, 0);
        acc[g][1] = __builtin_amdgcn_mfma_f32_16x16x32_bf16(wf[g][kk], h1, acc[g][1], 0, 0, 0);
        acc[g][2] = __builtin_amdgcn_mfma_f32_16x16x32_bf16(wf[g][kk], h2, acc[g][2], 0, 0, 0);
        acc[g][3] = __builtin_amdgcn_mfma_f32_16x16x32_bf16(wf[g][kk], h3, acc[g][3], 0, 0, 0);
      }
    }
    // partials: C row m = q*4+r, col b = bt*16+l15
#pragma unroll
    for (int g = 0; g < 3; ++g)
#pragma unroll
      for (int bt = 0; bt < 4; ++bt)
#pragma unroll
        for (int r = 0; r < 4; ++r)
          part[w][g][q * 4 + r][bt * 16 + l15] = acc[g][bt][r];
    __syncthreads();

    // reduce 4 waves + combine (b-fast: conflict-free LDS, regs hold xg)
#pragma unroll
    for (int i = 0; i < 4; ++i) {
      int e = tid + 256 * i;
      int m = e >> 6, b = e & 63;
      float hr = part[0][0][m][b] + part[1][0][m][b] + part[2][0][m][b] + part[3][0][m][b] + bh_lds[0][m];
      float hz = part[0][1][m][b] + part[1][1][m][b] + part[2][1][m][b] + part[3][1][m][b] + bh_lds[1][m];
      float hn = part[0][2][m][b] + part[1][2][m][b] + part[2][2][m][b] + part[3][2][m][b] + bh_lds[2][m];
      float xr = bf2f(xq[0][i]), xz = bf2f(xq[1][i]), xn = bf2f(xq[2][i]);
      float r = 1.f / (1.f + __expf(-(xr + hr)));
      float z = 1.f / (1.f + __expf(-(xz + hz)));
      float ex = __expf(2.f * (xn + r * hn));
      float n = 1.f - 2.f / (ex + 1.f);       // tanh
      float hold = hown[e];
      float hnew = (1.f - z) * n + z * hold;
      hown[e] = hnew;
      hstage[b * 20 + m] = f2bf(hnew);
    }
    __syncthreads();

    // write h_next: thread -> (b = tid>>2, m-quad = (tid&3)*4), 8B stores
    {
      int b = tid >> 2, mq = (tid & 3) * 4;
      u16x4 v = *(const u16x4*)&hstage[b * 20 + mq];
      *(u16x4*)(hnxt + (size_t)b * HDIM + j0 + mq) = v;
    }
    __syncthreads();   // all waves' h stores drained (vmcnt0) before release

    // device-wide barrier: release add, RELAXED polls, one acquire at exit
    if (tid == 0) {
      __hip_atomic_fetch_add(bar, 1u, __ATOMIC_RELEASE, __HIP_MEMORY_SCOPE_AGENT);
      unsigned target = 64u * (unsigned)(t + 1);
      unsigned spins = 0;
      while (__hip_atomic_load(bar, __ATOMIC_RELAXED, __HIP_MEMORY_SCOPE_AGENT) < target) {
        __builtin_amdgcn_s_sleep(1);
        if (++spins > 100000000u) break;  // safety: wrong answer beats a hang
      }
      (void)__hip_atomic_load(bar, __ATOMIC_ACQUIRE, __HIP_MEMORY_SCOPE_AGENT);
    }
    __syncthreads();
  }

  // final h -> out[b][j]  (fp32)
  {
    int b = tid >> 2, mq = (tid & 3) * 4;
#pragma unroll
    for (int r = 0; r < 4; ++r)
      out[(size_t)b * HDIM + j0 + mq + r] = hown[(mq + r) * 64 + b];
  }
}

// ---------------------------------------------------------------------------
extern "C" void kernel_launch(void* const* d_in, const int* in_sizes, int n_in,
                              void* d_out, int out_size, void* d_ws, size_t ws_size,
                              hipStream_t stream) {
  const float* U   = (const float*)d_in[0];
  const float* Wih = (const float*)d_in[1];
  const float* Whh = (const float*)d_in[2];
  const float* bih = (const float*)d_in[3];
  const float* bhh = (const float*)d_in[4];
  float* out = (float*)d_out;

  char* ws = (char*)d_ws;
  const size_t XG_BYTES = (size_t)S_LEN * GDIM * BATCH * 2;  // 201326592
  unsigned short* xg   = (unsigned short*)ws;
  unsigned short* hbuf = (unsigned short*)(ws + XG_BYTES);
  const size_t H_BYTES = (size_t)2 * BATCH * HDIM * 2;       // 262144
  unsigned int* bar    = (unsigned int*)(ws + XG_BYTES + H_BYTES);

  // zero h(0) double-buffer + barrier counter (ws is poisoned 0xAA each call)
  hipMemsetAsync(ws + XG_BYTES, 0, H_BYTES + 64, stream);

  hipLaunchKernelGGL(xg_gemm, dim3((32768 / 128) * (GDIM / 128)), dim3(256), 0, stream,
                     U, Wih, bih, xg);
  hipLaunchKernelGGL(gru_scan, dim3(64), dim3(256), 0, stream,
                     Whh, bhh, xg, hbuf, bar, out);
}